// Round 2
// baseline (120.016 us; speedup 1.0000x reference)
//
#include <hip/hip_runtime.h>
#include <math.h>

#define BSZ 15
#define NA 225
#define NW 572
#define NTHREADS 256

// WEIGHTS = {0, 5, 50, 500, 5000, 100000}
__device__ __forceinline__ float wscore(int pc, int oc) {
    const float W[7] = {0.f, 5.f, 50.f, 500.f, 5000.f, 100000.f, 100000.f};
    float sp = (oc == 0 && pc > 0) ? W[pc > 5 ? 5 : pc] : 0.f;
    float so = (pc == 0 && oc > 0) ? W[oc > 5 ? 5 : oc] : 0.f;
    return sp - so;
}

// Block reductions: wave-64 shuffle + 4-wave LDS combine. Leading
// __syncthreads protects scratch reuse across back-to-back calls.
__device__ __forceinline__ float blockReduceSum(float v, float* s) {
    #pragma unroll
    for (int off = 32; off > 0; off >>= 1) v += __shfl_down(v, off, 64);
    const int lane = threadIdx.x & 63, wid = threadIdx.x >> 6;
    __syncthreads();
    if (lane == 0) s[wid] = v;
    __syncthreads();
    return (s[0] + s[1]) + (s[2] + s[3]);
}

// Two independent sums in one shuffle/barrier round.
__device__ __forceinline__ float2 blockReduceSum2(float a, float b, float* s) {
    #pragma unroll
    for (int off = 32; off > 0; off >>= 1) {
        a += __shfl_down(a, off, 64);
        b += __shfl_down(b, off, 64);
    }
    const int lane = threadIdx.x & 63, wid = threadIdx.x >> 6;
    __syncthreads();
    if (lane == 0) { s[wid] = a; s[4 + wid] = b; }
    __syncthreads();
    return make_float2((s[0] + s[1]) + (s[2] + s[3]),
                       (s[4] + s[5]) + (s[6] + s[7]));
}

__device__ __forceinline__ float blockReduceMax(float v, float* s) {
    #pragma unroll
    for (int off = 32; off > 0; off >>= 1) v = fmaxf(v, __shfl_down(v, off, 64));
    const int lane = threadIdx.x & 63, wid = threadIdx.x >> 6;
    __syncthreads();
    if (lane == 0) s[wid] = v;
    __syncthreads();
    return fmaxf(fmaxf(s[0], s[1]), fmaxf(s[2], s[3]));
}

__global__ __launch_bounds__(NTHREADS) void heur_kernel(
    const int* __restrict__ boards, const int* __restrict__ cur,
    const float* __restrict__ pnoise, const float* __restrict__ vnoise,
    float* __restrict__ out, int B)
{
    const int b = blockIdx.x;
    const int tid = threadIdx.x;

    __shared__ int   sB[NA];
    __shared__ float sDelta[NA];
    __shared__ float sWin[NA];
    __shared__ float sRed[8];

    if (tid < NA) {
        sB[tid]     = boards[b * NA + tid];
        sDelta[tid] = 0.f;
        sWin[tid]   = 0.f;
    }
    const int player = cur[b];
    const int opp    = 3 - player;
    __syncthreads();

    // ---- window pass: base score + per-cell delta scatter + win marks ----
    // 572 windows over 256 threads -> exactly 3 fixed-trip iterations.
    float baseLocal = 0.f;
    #pragma unroll
    for (int it = 0; it < 3; ++it) {
        const int w = tid + it * NTHREADS;
        if (w >= NW) break;
        // decode window index -> (start cell, stride), matching Python order:
        // dir (0,1): 165 wins, (1,0): 165, (1,1): 121, (1,-1): 121
        int r, c, step;
        if (w < 165)      {              r = w / 11; c = w % 11;     step = 1;  }
        else if (w < 330) { int u = w - 165; r = u / 15; c = u % 15; step = 15; }
        else if (w < 451) { int u = w - 330; r = u / 11; c = u % 11; step = 16; }
        else              { int u = w - 451; r = u / 11; c = u % 11 + 4; step = 14; }
        const int idx = r * BSZ + c;

        int pc = 0, oc = 0;
        #pragma unroll
        for (int k = 0; k < 5; ++k) {
            const int v = sB[idx + k * step];
            pc += (v == player);
            oc += (v == opp);
        }
        const float s0 = wscore(pc, oc);
        const float s1 = wscore(pc + 1, oc);
        baseLocal += s0;
        const float d = s1 - s0;   // nonzero only when window isn't "mixed" (~26%)
        if (d != 0.f) {
            #pragma unroll
            for (int k = 0; k < 5; ++k) atomicAdd(&sDelta[idx + k * step], d);
        }
        if (pc == 4 && oc == 0) {
            #pragma unroll
            for (int k = 0; k < 5; ++k) sWin[idx + k * step] = 1.f;  // benign race
        }
    }

    const float base = blockReduceSum(baseLocal, sRed);  // internal syncs cover scatter

    // ---- per-cell logits ----
    float logit = 0.f;
    bool  valid = false;
    if (tid < NA) {
        const bool isEmpty = (sB[tid] == 0);
        if (!isEmpty)             logit = -1000000.f;
        else if (sWin[tid] > 0.f) logit = 100000.f;
        else                      logit = base + sDelta[tid];
        valid = (logit > -100000.f);
    }

    // ---- normalization stats over valid cells (two-pass var, as reference) ----
    const float2 ns   = blockReduceSum2((tid < NA && valid) ? 1.f : 0.f,
                                        (tid < NA && valid) ? logit : 0.f, sRed);
    const float nf    = ns.x;
    const float nsafe = fmaxf(nf, 1.f);
    const float mean  = ns.y / nsafe;
    const float dv    = (tid < NA && valid) ? (logit - mean) : 0.f;
    const float var   = blockReduceSum(dv * dv, sRed) / nsafe;
    const float std_  = fmaxf(1.f, sqrtf(var));

    if (tid < NA && valid && nf > 0.f)
        logit += pnoise[b * NA + tid] * 2.0f * std_;

    // ---- softmax over all 225 entries (invalid stay at -1e6, exp -> 0) ----
    const float x  = (tid < NA) ? logit * 0.03f : -INFINITY;
    const float m  = blockReduceMax(x, sRed);
    const float e  = (tid < NA) ? expf(x - m) : 0.f;
    const float se = blockReduceSum(e, sRed);
    if (tid < NA) out[b * NA + tid] = e / se;

    // ---- value head ----
    if (tid == 0) {
        float v = tanhf((base + vnoise[b] * 200.0f) / 3000.0f);
        v = fminf(0.95f, fmaxf(-0.95f, v));
        out[(size_t)B * NA + b] = v;
    }
}

extern "C" void kernel_launch(void* const* d_in, const int* in_sizes, int n_in,
                              void* d_out, int out_size, void* d_ws, size_t ws_size,
                              hipStream_t stream) {
    const int*   boards = (const int*)d_in[0];
    const int*   cur    = (const int*)d_in[1];
    const float* pn     = (const float*)d_in[2];
    const float* vn     = (const float*)d_in[3];
    float*       out    = (float*)d_out;
    const int B = in_sizes[1];  // current_player has B elements

    heur_kernel<<<B, NTHREADS, 0, stream>>>(boards, cur, pn, vn, out, B);
}

// Round 4
// 111.482 us; speedup vs baseline: 1.0766x; 1.0766x over previous
//
#include <hip/hip_runtime.h>
#include <math.h>

#define BSZ 15
#define NA  225
#define NW  572

// weight table as cndmask chain (NOT a dynamically-indexed array -> no memory op)
__device__ __forceinline__ float wtab(int n) {  // n >= 1; n>=5 -> 1e5
    return n == 1 ? 5.f : n == 2 ? 50.f : n == 3 ? 500.f : n == 4 ? 5000.f : 100000.f;
}
__device__ __forceinline__ float wscore(int pc, int oc) {
    if (oc == 0 && pc > 0) return wtab(pc);
    if (pc == 0 && oc > 0) return -wtab(oc);
    return 0.f;
}

__device__ __forceinline__ float wredSum(float v) {
    #pragma unroll
    for (int off = 32; off; off >>= 1) v += __shfl_xor(v, off, 64);
    return v;
}
__device__ __forceinline__ float wredMax(float v) {
    #pragma unroll
    for (int off = 32; off; off >>= 1) v = fmaxf(v, __shfl_xor(v, off, 64));
    return v;
}

// One wave = one board; 4 boards per 256-thread block; no __syncthreads anywhere.
// LDS ordering relies on per-wave in-order DS execution + __threadfence_block().
__global__ __launch_bounds__(256, 8) void heur_kernel(
    const int* __restrict__ boards, const int* __restrict__ cur,
    const float* __restrict__ pnoise, const float* __restrict__ vnoise,
    float* __restrict__ out, int B)
{
    const int wid  = threadIdx.x >> 6;
    const int lane = threadIdx.x & 63;
    const int b    = blockIdx.x * 4 + wid;

    __shared__ int   sB[4][NA];
    __shared__ float sDelta[4][NA];
    __shared__ float sWin[4][NA];

    if (b >= B) return;  // whole wave exits together; no barriers exist

    int*   __restrict__ bB = sB[wid];
    float* __restrict__ bD = sDelta[wid];
    float* __restrict__ bW = sWin[wid];

    const int player = cur[b];
    const int opp    = 3 - player;
    const int* __restrict__ gb = boards + (size_t)b * NA;

    #pragma unroll
    for (int j = 0; j < 4; ++j) {
        const int c = lane + 64 * j;
        if (c < NA) { bB[c] = gb[c]; bD[c] = 0.f; bW[c] = 0.f; }
    }
    __threadfence_block();  // order init writes before window-pass reads (same wave)

    // ---- window pass: 572 windows over 64 lanes = 9 rounds ----
    float baseLocal = 0.f;
    #pragma unroll
    for (int it = 0; it < 9; ++it) {
        const int w = lane + it * 64;
        if (w < NW) {
            // decode (start,stride) matching Python enumeration:
            // (0,1):165, (1,0):165, (1,1):121, (1,-1):121
            int r, c, step;
            if (w < 165)      {                  r = w / 11; c = w % 11;     step = 1;  }
            else if (w < 330) { const int u = w - 165; r = u / 15; c = u % 15;     step = 15; }
            else if (w < 451) { const int u = w - 330; r = u / 11; c = u % 11;     step = 16; }
            else              { const int u = w - 451; r = u / 11; c = u % 11 + 4; step = 14; }
            const int idx = r * BSZ + c;

            int pc = 0, oc = 0;
            #pragma unroll
            for (int k = 0; k < 5; ++k) {
                const int v = bB[idx + k * step];
                pc += (v == player);
                oc += (v == opp);
            }
            const float s0 = wscore(pc, oc);
            baseLocal += s0;
            const float d = wscore(pc + 1, oc) - s0;  // nonzero for ~26% of windows
            if (d != 0.f) {
                #pragma unroll
                for (int k = 0; k < 5; ++k) atomicAdd(&bD[idx + k * step], d);
            }
            if (pc == 4 && oc == 0) {
                #pragma unroll
                for (int k = 0; k < 5; ++k) bW[idx + k * step] = 1.f;  // benign race
            }
        }
    }
    __threadfence_block();  // drain scatter before per-cell gather (same wave)

    const float base = wredSum(baseLocal);

    // ---- per-cell logits, stats (4 cells/lane, all in registers) ----
    float logitv[4];
    float nLoc = 0.f, sLoc = 0.f;
    #pragma unroll
    for (int j = 0; j < 4; ++j) {
        const int c = lane + 64 * j;
        float lg = -1000000.f;
        if (c < NA) {
            if (bB[c] == 0) lg = (bW[c] > 0.f) ? 100000.f : base + bD[c];
        }
        logitv[j] = lg;
        if (c < NA && lg > -100000.f) { nLoc += 1.f; sLoc += lg; }
    }
    // fused {n, sum} butterfly
    #pragma unroll
    for (int off = 32; off; off >>= 1) {
        nLoc += __shfl_xor(nLoc, off, 64);
        sLoc += __shfl_xor(sLoc, off, 64);
    }
    const float nsafe = fmaxf(nLoc, 1.f);
    const float mean  = sLoc / nsafe;

    float vLoc = 0.f;
    #pragma unroll
    for (int j = 0; j < 4; ++j) {
        const int c = lane + 64 * j;
        if (c < NA && logitv[j] > -100000.f) {
            const float dv = logitv[j] - mean;
            vLoc += dv * dv;
        }
    }
    const float var  = wredSum(vLoc) / nsafe;
    const float std_ = fmaxf(1.f, sqrtf(var));
    const float nsc  = 2.0f * std_;
    const bool  anyValid = nLoc > 0.f;

    const float* __restrict__ pn = pnoise + (size_t)b * NA;
    #pragma unroll
    for (int j = 0; j < 4; ++j) {
        const int c = lane + 64 * j;
        if (c < NA && logitv[j] > -100000.f && anyValid)
            logitv[j] += pn[c] * nsc;
    }

    // ---- softmax over all 225 (invalid at -1e6 -> exp underflows to 0) ----
    float xs[4];
    float mLoc = -INFINITY;
    #pragma unroll
    for (int j = 0; j < 4; ++j) {
        const int c = lane + 64 * j;
        xs[j] = logitv[j] * 0.03f;           // hoisted scale (reused below)
        if (c < NA) mLoc = fmaxf(mLoc, xs[j]);
    }
    const float m = wredMax(mLoc);

    float ev[4];
    float eLoc = 0.f;
    #pragma unroll
    for (int j = 0; j < 4; ++j) {
        const int c = lane + 64 * j;
        ev[j] = (c < NA) ? __expf(xs[j] - m) : 0.f;
        eLoc += ev[j];
    }
    const float inv = 1.f / wredSum(eLoc);

    float* __restrict__ po = out + (size_t)b * NA;
    #pragma unroll
    for (int j = 0; j < 4; ++j) {
        const int c = lane + 64 * j;
        if (c < NA) po[c] = ev[j] * inv;
    }

    // ---- value head ----
    if (lane == 0) {
        float v = tanhf((base + vnoise[b] * 200.0f) / 3000.0f);
        v = fminf(0.95f, fmaxf(-0.95f, v));
        out[(size_t)B * NA + b] = v;
    }
}

extern "C" void kernel_launch(void* const* d_in, const int* in_sizes, int n_in,
                              void* d_out, int out_size, void* d_ws, size_t ws_size,
                              hipStream_t stream) {
    const int*   boards = (const int*)d_in[0];
    const int*   cur    = (const int*)d_in[1];
    const float* pn     = (const float*)d_in[2];
    const float* vn     = (const float*)d_in[3];
    float*       outp   = (float*)d_out;
    const int B = in_sizes[1];  // current_player has B elements

    const int grid = (B + 3) / 4;  // 4 boards per block (one per wave)
    heur_kernel<<<grid, 256, 0, stream>>>(boards, cur, pn, vn, outp, B);
}

// Round 5
// 109.810 us; speedup vs baseline: 1.0929x; 1.0152x over previous
//
#include <hip/hip_runtime.h>
#include <math.h>

#define BSZ 15
#define NA  225
typedef unsigned long long u64;

// weight table as cndmask chain (no dynamically-indexed array -> no scratch)
__device__ __forceinline__ float wtab(int n) {  // n >= 1; n>=5 -> 1e5
    return n == 1 ? 5.f : n == 2 ? 50.f : n == 3 ? 500.f : n == 4 ? 5000.f : 100000.f;
}
__device__ __forceinline__ float wscore(int pc, int oc) {
    if (oc == 0 && pc > 0) return wtab(pc);
    if (pc == 0 && oc > 0) return -wtab(oc);
    return 0.f;
}
__device__ __forceinline__ float wredSum(float v) {
    #pragma unroll
    for (int off = 32; off; off >>= 1) v += __shfl_xor(v, off, 64);
    return v;
}
__device__ __forceinline__ float wredMax(float v) {
    #pragma unroll
    for (int off = 32; off; off >>= 1) v = fmaxf(v, __shfl_xor(v, off, 64));
    return v;
}

struct Masks { u64 P0, P1, P2, P3, O0, O1, O2, O3; };

// Evaluate one window: bit-extract from wave-uniform bitboards, no LDS reads.
// STEP/DIV/CEXTRA/wmask are compile-time per direction-round.
template<int STEP, int DIV, int CEXTRA, bool HAS64>
__device__ __forceinline__ void doWin(int u, const Masks& M, u64 wmask,
                                      float* __restrict__ bD, float* __restrict__ bW,
                                      float& baseLocal)
{
    const int r   = u / DIV;            // compile-time divisor -> magic mul
    const int c   = u % DIV + CEXTRA;
    const int idx = r * BSZ + c;
    const int q = idx >> 6, sh = idx & 63;
    // dynamic chunk select (2-level cndmask), then 64-bit funnel shift.
    const u64 Plo = (q & 2) ? ((q & 1) ? M.P3 : M.P2) : ((q & 1) ? M.P1 : M.P0);
    const u64 Phi = (q & 2) ? ((q & 1) ? 0ULL : M.P3) : ((q & 1) ? M.P2 : M.P1);
    const u64 Olo = (q & 2) ? ((q & 1) ? M.O3 : M.O2) : ((q & 1) ? M.O1 : M.O0);
    const u64 Ohi = (q & 2) ? ((q & 1) ? 0ULL : M.O3) : ((q & 1) ? M.O2 : M.O1);
    const u64 xP = (Plo >> sh) | ((Phi << (63 - sh)) << 1);  // sh==0 safe
    const u64 xO = (Olo >> sh) | ((Ohi << (63 - sh)) << 1);
    int pc = __popcll(xP & wmask);
    int oc = __popcll(xO & wmask);
    if (HAS64) {  // step 16 window spans 65 bits; cell 4 = bit sh of hi chunk
        pc += (int)((Phi >> sh) & 1ULL);
        oc += (int)((Ohi >> sh) & 1ULL);
    }
    const float s0 = wscore(pc, oc);
    baseLocal += s0;
    const float d = wscore(pc + 1, oc) - s0;  // nonzero for ~26% of windows
    if (d != 0.f) {
        #pragma unroll
        for (int k = 0; k < 5; ++k) atomicAdd(&bD[idx + k * STEP], d);
    }
    if (pc == 4 && oc == 0) {
        #pragma unroll
        for (int k = 0; k < 5; ++k) bW[idx + k * STEP] = 1.f;  // benign race
    }
}

// One wave = one board, 4 boards/block, no __syncthreads. Board lives in
// ballot-built bitmasks (SGPRs); LDS only for delta scatter + win marks.
__global__ __launch_bounds__(256, 8) void heur_kernel(
    const int* __restrict__ boards, const int* __restrict__ cur,
    const float* __restrict__ pnoise, const float* __restrict__ vnoise,
    float* __restrict__ out, int B)
{
    const int wid  = threadIdx.x >> 6;
    const int lane = threadIdx.x & 63;
    const int b    = blockIdx.x * 4 + wid;

    __shared__ float sDelta[4][NA];
    __shared__ float sWin[4][NA];

    if (b >= B) return;  // whole wave exits together

    float* __restrict__ bD = sDelta[wid];
    float* __restrict__ bW = sWin[wid];

    const int player = cur[b];
    const int opp    = 3 - player;
    const int* __restrict__ gb = boards + (size_t)b * NA;

    // board cells for this lane: c = lane + 64j  (chunk j, bit position = lane)
    const int v0 = gb[lane];
    const int v1 = gb[lane + 64];
    const int v2 = gb[lane + 128];
    const int v3 = (lane + 192 < NA) ? gb[lane + 192] : -1;

    // issue noise loads early: latency hides under the VALU-only window pass
    const float* __restrict__ pn = pnoise + (size_t)b * NA;
    float pnv[4];
    pnv[0] = pn[lane];
    pnv[1] = pn[lane + 64];
    pnv[2] = pn[lane + 128];
    pnv[3] = (lane + 192 < NA) ? pn[lane + 192] : 0.f;
    const float vnb = vnoise[b];

    Masks M;
    M.P0 = __ballot(v0 == player); M.O0 = __ballot(v0 == opp);
    M.P1 = __ballot(v1 == player); M.O1 = __ballot(v1 == opp);
    M.P2 = __ballot(v2 == player); M.O2 = __ballot(v2 == opp);
    M.P3 = __ballot(v3 == player); M.O3 = __ballot(v3 == opp);

    // init scatter buffers
    bD[lane] = 0.f;       bW[lane] = 0.f;
    bD[lane + 64] = 0.f;  bW[lane + 64] = 0.f;
    bD[lane + 128] = 0.f; bW[lane + 128] = 0.f;
    if (lane + 192 < NA) { bD[lane + 192] = 0.f; bW[lane + 192] = 0.f; }
    __threadfence_block();

    // ---- window pass, direction-major (constants per round) ----
    // (0,1):165 step1 div11 | (1,0):165 step15 div15 | (1,1):121 step16 div11
    // | (1,-1):121 step14 div11 c+=4
    float baseLocal = 0.f;
    doWin<1, 11, 0, false>(lane,       M, 0x1FULL, bD, bW, baseLocal);
    doWin<1, 11, 0, false>(lane + 64,  M, 0x1FULL, bD, bW, baseLocal);
    if (lane < 37)
        doWin<1, 11, 0, false>(lane + 128, M, 0x1FULL, bD, bW, baseLocal);
    doWin<15, 15, 0, false>(lane,      M, 0x1000200040008001ULL, bD, bW, baseLocal);
    doWin<15, 15, 0, false>(lane + 64, M, 0x1000200040008001ULL, bD, bW, baseLocal);
    if (lane < 37)
        doWin<15, 15, 0, false>(lane + 128, M, 0x1000200040008001ULL, bD, bW, baseLocal);
    doWin<16, 11, 0, true>(lane,       M, 0x0001000100010001ULL, bD, bW, baseLocal);
    if (lane < 57)
        doWin<16, 11, 0, true>(lane + 64, M, 0x0001000100010001ULL, bD, bW, baseLocal);
    doWin<14, 11, 4, false>(lane,      M, 0x0100040010004001ULL, bD, bW, baseLocal);
    if (lane < 57)
        doWin<14, 11, 4, false>(lane + 64, M, 0x0100040010004001ULL, bD, bW, baseLocal);

    __threadfence_block();  // drain same-wave scatter before gather

    const float base = wredSum(baseLocal);

    // occupancy chunks for the empty test (bit lane of chunk j == cell lane+64j)
    const u64 C0 = M.P0 | M.O0, C1 = M.P1 | M.O1, C2 = M.P2 | M.O2, C3 = M.P3 | M.O3;

    // ---- per-cell logits + stats (4 cells/lane, registers) ----
    float logitv[4];
    float nLoc = 0.f, sLoc = 0.f;
    #pragma unroll
    for (int j = 0; j < 4; ++j) {
        const int c = lane + 64 * j;
        float lg = -1000000.f;
        if (c < NA) {
            const u64 Cj = j == 0 ? C0 : j == 1 ? C1 : j == 2 ? C2 : C3;
            const bool isEmpty = ((Cj >> lane) & 1ULL) == 0ULL;
            if (isEmpty) lg = (bW[c] > 0.f) ? 100000.f : base + bD[c];
        }
        logitv[j] = lg;
        if (c < NA && lg > -100000.f) { nLoc += 1.f; sLoc += lg; }
    }
    #pragma unroll
    for (int off = 32; off; off >>= 1) {
        nLoc += __shfl_xor(nLoc, off, 64);
        sLoc += __shfl_xor(sLoc, off, 64);
    }
    const float nsafe = fmaxf(nLoc, 1.f);
    const float mean  = sLoc / nsafe;

    float vLoc = 0.f;
    #pragma unroll
    for (int j = 0; j < 4; ++j) {
        const int c = lane + 64 * j;
        if (c < NA && logitv[j] > -100000.f) {
            const float dv = logitv[j] - mean;
            vLoc += dv * dv;
        }
    }
    const float var  = wredSum(vLoc) / nsafe;
    const float std_ = fmaxf(1.f, sqrtf(var));
    const float nsc  = 2.0f * std_;
    const bool  anyValid = nLoc > 0.f;

    #pragma unroll
    for (int j = 0; j < 4; ++j) {
        const int c = lane + 64 * j;
        if (c < NA && logitv[j] > -100000.f && anyValid)
            logitv[j] += pnv[j] * nsc;
    }

    // ---- softmax over all 225 (invalid at -1e6 -> exp underflows to 0) ----
    float xs[4];
    float mLoc = -INFINITY;
    #pragma unroll
    for (int j = 0; j < 4; ++j) {
        const int c = lane + 64 * j;
        xs[j] = logitv[j] * 0.03f;
        if (c < NA) mLoc = fmaxf(mLoc, xs[j]);
    }
    const float m = wredMax(mLoc);

    float ev[4];
    float eLoc = 0.f;
    #pragma unroll
    for (int j = 0; j < 4; ++j) {
        const int c = lane + 64 * j;
        ev[j] = (c < NA) ? __expf(xs[j] - m) : 0.f;
        eLoc += ev[j];
    }
    const float inv = 1.f / wredSum(eLoc);

    float* __restrict__ po = out + (size_t)b * NA;
    #pragma unroll
    for (int j = 0; j < 4; ++j) {
        const int c = lane + 64 * j;
        if (c < NA) po[c] = ev[j] * inv;
    }

    // ---- value head ----
    if (lane == 0) {
        float v = tanhf((base + vnb * 200.0f) / 3000.0f);
        v = fminf(0.95f, fmaxf(-0.95f, v));
        out[(size_t)B * NA + b] = v;
    }
}

extern "C" void kernel_launch(void* const* d_in, const int* in_sizes, int n_in,
                              void* d_out, int out_size, void* d_ws, size_t ws_size,
                              hipStream_t stream) {
    const int*   boards = (const int*)d_in[0];
    const int*   cur    = (const int*)d_in[1];
    const float* pn     = (const float*)d_in[2];
    const float* vn     = (const float*)d_in[3];
    float*       outp   = (float*)d_out;
    const int B = in_sizes[1];  // current_player has B elements

    const int grid = (B + 3) / 4;  // 4 boards per block (one per wave)
    heur_kernel<<<grid, 256, 0, stream>>>(boards, cur, pn, vn, outp, B);
}